// Round 4
// baseline (248.689 us; speedup 1.0000x reference)
//
#include <hip/hip_runtime.h>
#include <hip/hip_bf16.h>

// Problem constants (B=4, S=2048, D=512, H=8, Dh=64)
#define BATCH 4
#define SEQ   2048
#define DIM   512
#define NH    8
#define DH    64
#define NTOK  (BATCH*SEQ)        // 8192

typedef __bf16 bf16x8 __attribute__((ext_vector_type(8)));
typedef float  f32x4  __attribute__((ext_vector_type(4)));

#define MFMA16(a,b,c) __builtin_amdgcn_mfma_f32_16x16x32_bf16((a),(b),(c),0,0,0)

// async global->LDS, 16B per lane; LDS dest = wave-uniform base + lane*16
__device__ __forceinline__ void async_ld16(const __bf16* g, __bf16* l) {
  __builtin_amdgcn_global_load_lds(
      (const __attribute__((address_space(1))) void*)g,
      (__attribute__((address_space(3))) void*)l, 16, 0, 0);
}

// ---------------------------------------------------------------------------
// fp32 -> bf16 converts
// ---------------------------------------------------------------------------
__global__ __launch_bounds__(256) void cvt_f32_bf16(const float* __restrict__ src,
                                                    __bf16* __restrict__ dst, int n8) {
  int i = blockIdx.x * blockDim.x + threadIdx.x;
  if (i >= n8) return;
  const float4* s = (const float4*)src;
  float4 a = s[2*i], b = s[2*i+1];
  bf16x8 o;
  o[0] = (__bf16)a.x; o[1] = (__bf16)a.y; o[2] = (__bf16)a.z; o[3] = (__bf16)a.w;
  o[4] = (__bf16)b.x; o[5] = (__bf16)b.y; o[6] = (__bf16)b.z; o[7] = (__bf16)b.w;
  *(bf16x8*)&dst[8*i] = o;
}

__global__ __launch_bounds__(256) void cvt_weights(
    const float* __restrict__ s0, const float* __restrict__ s1,
    const float* __restrict__ s2, const float* __restrict__ s3,
    __bf16* __restrict__ o0, __bf16* __restrict__ o1,
    __bf16* __restrict__ o2, __bf16* __restrict__ o3) {
  int i = blockIdx.x * blockDim.x + threadIdx.x;
  const int which = i >> 15, off = i & 32767;
  const float* src = (which == 0) ? s0 : (which == 1) ? s1 : (which == 2) ? s2 : s3;
  __bf16* dst      = (which == 0) ? o0 : (which == 1) ? o1 : (which == 2) ? o2 : o3;
  const float4* s = (const float4*)src;
  float4 a = s[2*off], b = s[2*off+1];
  bf16x8 o;
  o[0] = (__bf16)a.x; o[1] = (__bf16)a.y; o[2] = (__bf16)a.z; o[3] = (__bf16)a.w;
  o[4] = (__bf16)b.x; o[5] = (__bf16)b.y; o[6] = (__bf16)b.z; o[7] = (__bf16)b.w;
  *(bf16x8*)&dst[8*off] = o;
}

// ---------------------------------------------------------------------------
// NT GEMM 128x128, m97-style global_load_lds staging (unpadded LDS stride 64),
// LDS-swizzle epilogue with coalesced 16B stores.
// z = 0/1/2 -> Q / K / V; Q,K stored [B,H,S,Dh]; V stored [B,H,Dh,S]
// ---------------------------------------------------------------------------
__global__ __launch_bounds__(256) void gemm_qkv(
    const __bf16* __restrict__ xb,
    const __bf16* __restrict__ wq, const __bf16* __restrict__ wk,
    const __bf16* __restrict__ wv,
    const float* __restrict__ bq, const float* __restrict__ bk,
    const float* __restrict__ bv,
    __bf16* __restrict__ Qb, __bf16* __restrict__ Kb, __bf16* __restrict__ Vt)
{
  const int z = blockIdx.z;
  const __bf16* W    = (z == 0) ? wq : (z == 1) ? wk : wv;
  const float*  bias = (z == 0) ? bq : (z == 1) ? bk : bv;

  __shared__ __bf16 S[2][128*64];          // As, Bs; reused as C-stage (32 KB)
  __bf16* As = S[0];
  __bf16* Bs = S[1];

  const int tid  = threadIdx.x;
  const int m0   = blockIdx.x * 128, n0 = blockIdx.y * 128;
  const int w    = tid >> 6, lane = tid & 63, quad = lane >> 4, l16 = lane & 15;
  const int wm   = (w >> 1) * 64, wn = (w & 1) * 64;
  const int lrow = lane >> 3;              // 0..7
  const int lcol = (lane & 7) * 8;         // element col within 64

  f32x4 acc[4][4] = {};

  const __bf16* Ag = xb + (size_t)m0 * DIM;
  const __bf16* Bg = W  + (size_t)n0 * DIM;

  for (int k0 = 0; k0 < DIM; k0 += 64) {
    // stage: wave w rows [w*32, w*32+32), 4 x 1KB DMA per operand
#pragma unroll
    for (int i = 0; i < 4; ++i) {
      const int rb = w*32 + i*8;
      async_ld16(&Ag[(size_t)(rb + lrow)*DIM + k0 + lcol], &As[rb*64]);
      async_ld16(&Bg[(size_t)(rb + lrow)*DIM + k0 + lcol], &Bs[rb*64]);
    }
    __syncthreads();
#pragma unroll
    for (int kk = 0; kk < 2; ++kk) {
      const int ko = kk*32 + quad*8;
      bf16x8 af[4], bfr[4];
#pragma unroll
      for (int f = 0; f < 4; ++f) {
        af[f]  = *(const bf16x8*)&As[(wm + f*16 + l16)*64 + ko];
        bfr[f] = *(const bf16x8*)&Bs[(wn + f*16 + l16)*64 + ko];
      }
#pragma unroll
      for (int fm = 0; fm < 4; ++fm)
#pragma unroll
        for (int fn = 0; fn < 4; ++fn)
          acc[fm][fn] = MFMA16(af[fm], bfr[fn], acc[fm][fn]);
    }
    __syncthreads();
  }

  // ---- epilogue: acc -> swizzled LDS tile -> coalesced 16B stores ----
  // phys addr = row*128 + ((chunk ^ (row&7))<<3) + (col&7)
  __bf16* Cs = &S[0][0];                   // 128*128 bf16 = 32 KB (all of S)
  if (z < 2) {
#pragma unroll
    for (int fm = 0; fm < 4; ++fm)
#pragma unroll
      for (int fn = 0; fn < 4; ++fn) {
        const int col = wn + fn*16 + l16;
        const float bc = bias[n0 + col];
        const int chunk = col >> 3, ce = col & 7;
#pragma unroll
        for (int r = 0; r < 4; ++r) {
          const int row = wm + fm*16 + quad*4 + r;
          Cs[row*128 + ((chunk ^ (row & 7)) << 3) + ce] = (__bf16)(acc[fm][fn][r] + bc);
        }
      }
  } else {
    // transposed stage: Cs[dhcol][s], 4 consecutive s per (fm,fn) -> b64 write
#pragma unroll
    for (int fm = 0; fm < 4; ++fm)
#pragma unroll
      for (int fn = 0; fn < 4; ++fn) {
        const int dhcol = wn + fn*16 + l16;
        const float bc = bias[n0 + dhcol];
        const int sbase = wm + fm*16 + quad*4;
        const int schunk = sbase >> 3, so = sbase & 7;   // so in {0,4}
        __bf16* p = &Cs[dhcol*128 + ((schunk ^ (dhcol & 7)) << 3) + so];
#pragma unroll
        for (int r = 0; r < 4; ++r)
          p[r] = (__bf16)(acc[fm][fn][r] + bc);
      }
  }
  __syncthreads();
  {
    const int row = tid >> 1, half = tid & 1;
    if (z < 2) {
      __bf16* O = (z == 0) ? Qb : Kb;
      const int s = m0 + row, bb = s >> 11, ss = s & 2047;
#pragma unroll
      for (int j = 0; j < 8; ++j) {
        const int chunk = half*8 + j;
        bf16x8 v = *(const bf16x8*)&Cs[row*128 + ((chunk ^ (row & 7)) << 3)];
        const int colg = n0 + chunk*8;
        const int hh = colg >> 6, dh = colg & 63;
        *(bf16x8*)&O[((size_t)(bb*NH + hh)*SEQ + ss)*DH + dh] = v;
      }
    } else {
      const int colg = n0 + row;           // dh column
      const int hh = colg >> 6, dh = colg & 63;
      const int bb = m0 >> 11, s0s = m0 & 2047;
#pragma unroll
      for (int j = 0; j < 8; ++j) {
        const int chunk = half*8 + j;
        bf16x8 v = *(const bf16x8*)&Cs[row*128 + ((chunk ^ (row & 7)) << 3)];
        *(bf16x8*)&Vt[((size_t)(bb*NH + hh)*DH + dh)*SEQ + s0s + chunk*8] = v;
      }
    }
  }
}

// ---------------------------------------------------------------------------
// Output projection with the same staging; direct f32 stores.
// ---------------------------------------------------------------------------
__global__ __launch_bounds__(256) void gemm_out(
    const __bf16* __restrict__ attnb, const __bf16* __restrict__ wo,
    const float* __restrict__ bo, float* __restrict__ out)
{
  __shared__ __bf16 S[2][128*64];
  __bf16* As = S[0];
  __bf16* Bs = S[1];

  const int tid = threadIdx.x;
  const int m0  = blockIdx.x * 128, n0 = blockIdx.y * 128;
  const int w   = tid >> 6, lane = tid & 63, quad = lane >> 4, l16 = lane & 15;
  const int wm  = (w >> 1) * 64, wn = (w & 1) * 64;
  const int lrow = lane >> 3, lcol = (lane & 7) * 8;

  f32x4 acc[4][4] = {};

  const __bf16* Ag = attnb + (size_t)m0 * DIM;
  const __bf16* Bg = wo    + (size_t)n0 * DIM;

  for (int k0 = 0; k0 < DIM; k0 += 64) {
#pragma unroll
    for (int i = 0; i < 4; ++i) {
      const int rb = w*32 + i*8;
      async_ld16(&Ag[(size_t)(rb + lrow)*DIM + k0 + lcol], &As[rb*64]);
      async_ld16(&Bg[(size_t)(rb + lrow)*DIM + k0 + lcol], &Bs[rb*64]);
    }
    __syncthreads();
#pragma unroll
    for (int kk = 0; kk < 2; ++kk) {
      const int ko = kk*32 + quad*8;
      bf16x8 af[4], bfr[4];
#pragma unroll
      for (int f = 0; f < 4; ++f) {
        af[f]  = *(const bf16x8*)&As[(wm + f*16 + l16)*64 + ko];
        bfr[f] = *(const bf16x8*)&Bs[(wn + f*16 + l16)*64 + ko];
      }
#pragma unroll
      for (int fm = 0; fm < 4; ++fm)
#pragma unroll
        for (int fn = 0; fn < 4; ++fn)
          acc[fm][fn] = MFMA16(af[fm], bfr[fn], acc[fm][fn]);
    }
    __syncthreads();
  }

#pragma unroll
  for (int fm = 0; fm < 4; ++fm) {
#pragma unroll
    for (int fn = 0; fn < 4; ++fn) {
      const int col  = n0 + wn + fn*16 + l16;
      const float bc = bo[col];
#pragma unroll
      for (int r = 0; r < 4; ++r) {
        const int row = m0 + wm + fm*16 + quad*4 + r;
        out[(size_t)row*DIM + col] = acc[fm][fn][r] + bc;
      }
    }
  }
}

// ---------------------------------------------------------------------------
// Flash attention v4: 2048 blocks x 4 waves. The 4 waves of a block split the
// key range of one (bh, 32-q-row tile) into <=8-tile chunks (split-K), then
// merge (m,l,O) through LDS. Critical path: 33 -> 8 tiles; 12 waves/CU.
// ---------------------------------------------------------------------------
__global__ __launch_bounds__(256) void flash_attn(
    const __bf16* __restrict__ Qb, const __bf16* __restrict__ Kb,
    const __bf16* __restrict__ Vt, __bf16* __restrict__ attnb)
{
  const int idx = blockIdx.x;
  const int bh  = idx & 31;
  const int qt  = 63 - (idx >> 5);             // heavy q-tiles first
  const int b   = bh >> 3, h = bh & 7;
  const int tid = threadIdx.x;
  const int w   = tid >> 6, lane = tid & 63, quad = lane >> 4, l16 = lane & 15;
  const int q0  = qt * 32;

  const __bf16* Qp = Qb + (size_t)bh * SEQ * DH;   // [s][dh]
  const __bf16* Kp = Kb + (size_t)bh * SEQ * DH;   // [s][dh]
  const __bf16* Vp = Vt + (size_t)bh * DH * SEQ;   // [dh][s]

  __shared__ __bf16 Plds[4][32*72];            // per-wave P transpose patch
  __shared__ float  OaccL[32*68];              // stride 68: 2-way conflicts
  __shared__ float  mL[4][32], lL[4][32];
  __bf16* Pw = Plds[w];

  // Q fragments, pre-scaled by 1/sqrt(Dh)=0.125
  bf16x8 qf[2][2];
#pragma unroll
  for (int mf = 0; mf < 2; ++mf)
#pragma unroll
    for (int kk = 0; kk < 2; ++kk) {
      bf16x8 q = *(const bf16x8*)&Qp[(size_t)(q0 + mf*16 + l16)*DH + kk*32 + quad*8];
#pragma unroll
      for (int j = 0; j < 8; ++j) q[j] = (__bf16)((float)q[j] * 0.125f);
      qf[mf][kk] = q;
    }

  f32x4 of[2][4] = {};
  float m_[2][4], l_[2][4];
#pragma unroll
  for (int mf = 0; mf < 2; ++mf)
#pragma unroll
    for (int r = 0; r < 4; ++r) { m_[mf][r] = -1e30f; l_[mf][r] = 0.f; }

  const int nt  = (q0 >> 6) + 1;               // total 64-key tiles (<=32)
  const int c   = (nt + 3) >> 2;               // chunk tiles per wave (<=8)
  const int ktb = w * c;
  const int kte = (ktb + c < nt) ? (ktb + c) : nt;

  if (ktb < kte) {
    bf16x8 kfA[4][2], kfB[4][2];
#pragma unroll
    for (int fn = 0; fn < 4; ++fn)
#pragma unroll
      for (int kk = 0; kk < 2; ++kk)
        kfA[fn][kk] = *(const bf16x8*)&Kp[(size_t)(ktb*64 + fn*16 + l16)*DH + kk*32 + quad*8];

#define TILE_STEP(KC, KN, KT)                                                  \
  {                                                                            \
    const int k0 = (KT) * 64;                                                  \
    bf16x8 vf[4][2];                                                           \
    _Pragma("unroll")                                                          \
    for (int nd = 0; nd < 4; ++nd)                                             \
      _Pragma("unroll")                                                        \
      for (int kq = 0; kq < 2; ++kq)                                           \
        vf[nd][kq] = *(const bf16x8*)&Vp[(size_t)(nd*16 + l16)*SEQ + k0 +      \
                                         kq*32 + quad*8];                      \
    {                                                                          \
      const int kn0 = ((KT) + 1 < kte) ? k0 + 64 : k0;                         \
      _Pragma("unroll")                                                        \
      for (int fn = 0; fn < 4; ++fn)                                           \
        _Pragma("unroll")                                                      \
        for (int kk = 0; kk < 2; ++kk)                                         \
          KN[fn][kk] = *(const bf16x8*)&Kp[(size_t)(kn0 + fn*16 + l16)*DH +    \
                                           kk*32 + quad*8];                    \
    }                                                                          \
    f32x4 sf[2][4] = {};                                                       \
    _Pragma("unroll")                                                          \
    for (int mf = 0; mf < 2; ++mf)                                             \
      _Pragma("unroll")                                                        \
      for (int fn = 0; fn < 4; ++fn) {                                         \
        sf[mf][fn] = MFMA16(qf[mf][0], KC[fn][0], sf[mf][fn]);                 \
        sf[mf][fn] = MFMA16(qf[mf][1], KC[fn][1], sf[mf][fn]);                 \
      }                                                                        \
    if (k0 + 63 > q0) {                                                        \
      _Pragma("unroll")                                                        \
      for (int mf = 0; mf < 2; ++mf)                                           \
        _Pragma("unroll")                                                      \
        for (int fn = 0; fn < 4; ++fn) {                                       \
          const int col = k0 + fn*16 + l16;                                    \
          _Pragma("unroll")                                                    \
          for (int r = 0; r < 4; ++r) {                                        \
            const int row = q0 + mf*16 + quad*4 + r;                           \
            if (col > row) sf[mf][fn][r] = -1e30f;                             \
          }                                                                    \
        }                                                                      \
    }                                                                          \
    float rmax[2][4];                                                          \
    _Pragma("unroll")                                                          \
    for (int mf = 0; mf < 2; ++mf)                                             \
      _Pragma("unroll")                                                        \
      for (int r = 0; r < 4; ++r)                                              \
        rmax[mf][r] = fmaxf(fmaxf(sf[mf][0][r], sf[mf][1][r]),                 \
                            fmaxf(sf[mf][2][r], sf[mf][3][r]));                \
    _Pragma("unroll")                                                          \
    for (int d = 1; d < 16; d <<= 1)                                           \
      _Pragma("unroll")                                                        \
      for (int mf = 0; mf < 2; ++mf)                                           \
        _Pragma("unroll")                                                      \
        for (int r = 0; r < 4; ++r)                                            \
          rmax[mf][r] = fmaxf(rmax[mf][r], __shfl_xor(rmax[mf][r], d));        \
    _Pragma("unroll")                                                          \
    for (int mf = 0; mf < 2; ++mf)                                             \
      _Pragma("unroll")                                                        \
      for (int r = 0; r < 4; ++r) {                                            \
        const float mn = fmaxf(m_[mf][r], rmax[mf][r]);                        \
        const float al = __expf(m_[mf][r] - mn);                               \
        m_[mf][r] = mn;                                                        \
        l_[mf][r] *= al;                                                       \
        _Pragma("unroll")                                                      \
        for (int nd = 0; nd < 4; ++nd) of[mf][nd][r] *= al;                    \
      }                                                                        \
    _Pragma("unroll")                                                          \
    for (int mf = 0; mf < 2; ++mf)                                             \
      _Pragma("unroll")                                                        \
      for (int fn = 0; fn < 4; ++fn)                                           \
        _Pragma("unroll")                                                      \
        for (int r = 0; r < 4; ++r)                                            \
          sf[mf][fn][r] = __expf(sf[mf][fn][r] - m_[mf][r]);                   \
    float rsum[2][4];                                                          \
    _Pragma("unroll")                                                          \
    for (int mf = 0; mf < 2; ++mf)                                             \
      _Pragma("unroll")                                                        \
      for (int r = 0; r < 4; ++r)                                              \
        rsum[mf][r] = (sf[mf][0][r] + sf[mf][1][r]) +                          \
                      (sf[mf][2][r] + sf[mf][3][r]);                           \
    _Pragma("unroll")                                                          \
    for (int d = 1; d < 16; d <<= 1)                                           \
      _Pragma("unroll")                                                        \
      for (int mf = 0; mf < 2; ++mf)                                           \
        _Pragma("unroll")                                                      \
        for (int r = 0; r < 4; ++r)                                            \
          rsum[mf][r] += __shfl_xor(rsum[mf][r], d);                           \
    _Pragma("unroll")                                                          \
    for (int mf = 0; mf < 2; ++mf)                                             \
      _Pragma("unroll")                                                        \
      for (int r = 0; r < 4; ++r) l_[mf][r] += rsum[mf][r];                    \
    _Pragma("unroll")                                                          \
    for (int mf = 0; mf < 2; ++mf)                                             \
      _Pragma("unroll")                                                        \
      for (int fn = 0; fn < 4; ++fn)                                           \
        _Pragma("unroll")                                                      \
        for (int r = 0; r < 4; ++r)                                            \
          Pw[(mf*16 + quad*4 + r)*72 + fn*16 + l16] = (__bf16)sf[mf][fn][r];   \
    bf16x8 pa[2][2];                                                           \
    _Pragma("unroll")                                                          \
    for (int mf = 0; mf < 2; ++mf)                                             \
      _Pragma("unroll")                                                        \
      for (int kq = 0; kq < 2; ++kq)                                           \
        pa[mf][kq] = *(const bf16x8*)&Pw[(mf*16 + l16)*72 + kq*32 + quad*8];   \
    _Pragma("unroll")                                                          \
    for (int mf = 0; mf < 2; ++mf)                                             \
      _Pragma("unroll")                                                        \
      for (int nd = 0; nd < 4; ++nd) {                                         \
        of[mf][nd] = MFMA16(pa[mf][0], vf[nd][0], of[mf][nd]);                 \
        of[mf][nd] = MFMA16(pa[mf][1], vf[nd][1], of[mf][nd]);                 \
      }                                                                        \
  }

    for (int kt = ktb; kt < kte; kt += 2) {
      TILE_STEP(kfA, kfB, kt);
      if (kt + 1 < kte) TILE_STEP(kfB, kfA, kt + 1);
    }
#undef TILE_STEP
  }

  // ---- cross-wave merge through LDS ----
  // 1) publish per-wave m,l  (16 lanes write identical values: benign)
#pragma unroll
  for (int mf = 0; mf < 2; ++mf)
#pragma unroll
    for (int r = 0; r < 4; ++r) {
      const int row = mf*16 + quad*4 + r;
      mL[w][row] = m_[mf][r];
      lL[w][row] = l_[mf][r];
    }
  __syncthreads();

  // 2) rescale own O by alpha_w = exp(m_w - M)
#pragma unroll
  for (int mf = 0; mf < 2; ++mf)
#pragma unroll
    for (int r = 0; r < 4; ++r) {
      const int row = mf*16 + quad*4 + r;
      const float M = fmaxf(fmaxf(mL[0][row], mL[1][row]),
                            fmaxf(mL[2][row], mL[3][row]));
      const float al = __expf(m_[mf][r] - M);
#pragma unroll
      for (int nd = 0; nd < 4; ++nd) of[mf][nd][r] *= al;
    }

  // 3) serialized f32 accumulation (wave 0 stores, waves 1-3 add)
  for (int ww = 0; ww < 4; ++ww) {
    if (w == ww) {
#pragma unroll
      for (int mf = 0; mf < 2; ++mf)
#pragma unroll
        for (int nd = 0; nd < 4; ++nd)
#pragma unroll
          for (int r = 0; r < 4; ++r) {
            const int a = (mf*16 + quad*4 + r)*68 + nd*16 + l16;
            if (ww == 0) OaccL[a] = of[mf][nd][r];
            else         OaccL[a] += of[mf][nd][r];
          }
    }
    __syncthreads();
  }

  // 4) normalize + store: thread -> (row = tid>>3, 8 dh at (tid&7)*8)
  {
    const int row = tid >> 3, d0 = (tid & 7) * 8;
    const float M = fmaxf(fmaxf(mL[0][row], mL[1][row]),
                          fmaxf(mL[2][row], mL[3][row]));
    float lt = 0.f;
#pragma unroll
    for (int ww = 0; ww < 4; ++ww)
      lt += __expf(mL[ww][row] - M) * lL[ww][row];
    const float inv = 1.0f / lt;
    bf16x8 o;
#pragma unroll
    for (int j = 0; j < 8; ++j)
      o[j] = (__bf16)(OaccL[row*68 + d0 + j] * inv);
    *(bf16x8*)&attnb[((size_t)b*SEQ + q0 + row)*DIM + h*DH + d0] = o;
  }
}

// ---------------------------------------------------------------------------
extern "C" void kernel_launch(void* const* d_in, const int* in_sizes, int n_in,
                              void* d_out, int out_size, void* d_ws, size_t ws_size,
                              hipStream_t stream) {
  const float* x  = (const float*)d_in[0];
  // d_in[1] = causal mask, unused (causality computed analytically)
  const float* Wq = (const float*)d_in[2];
  const float* bq = (const float*)d_in[3];
  const float* Wk = (const float*)d_in[4];
  const float* bk = (const float*)d_in[5];
  const float* Wv = (const float*)d_in[6];
  const float* bv = (const float*)d_in[7];
  const float* Wo = (const float*)d_in[8];
  const float* bo = (const float*)d_in[9];
  float* out = (float*)d_out;

  // workspace carve-up (bf16 elements), total ~42 MB
  __bf16* xb    = (__bf16*)d_ws;
  __bf16* wq    = xb + (size_t)NTOK*DIM;
  __bf16* wk    = wq + DIM*DIM;
  __bf16* wv    = wk + DIM*DIM;
  __bf16* wo    = wv + DIM*DIM;
  __bf16* Qb    = wo + DIM*DIM;
  __bf16* Kb    = Qb + (size_t)NTOK*DIM;
  __bf16* Vt    = Kb + (size_t)NTOK*DIM;
  __bf16* attnb = Vt + (size_t)NTOK*DIM;

  cvt_f32_bf16<<<(NTOK*DIM/8)/256, 256, 0, stream>>>(x, xb, NTOK*DIM/8);
  cvt_weights<<<(4*DIM*DIM/8)/256, 256, 0, stream>>>(Wq, Wk, Wv, Wo, wq, wk, wv, wo);

  gemm_qkv<<<dim3(NTOK/128, DIM/128, 3), 256, 0, stream>>>(
      xb, wq, wk, wv, bq, bk, bv, Qb, Kb, Vt);

  flash_attn<<<2048, 256, 0, stream>>>(Qb, Kb, Vt, attnb);

  gemm_out<<<dim3(NTOK/128, DIM/128), 256, 0, stream>>>(attnb, wo, bo, out);
}

// Round 5
// 236.103 us; speedup vs baseline: 1.0533x; 1.0533x over previous
//
#include <hip/hip_runtime.h>
#include <hip/hip_bf16.h>

// Problem constants (B=4, S=2048, D=512, H=8, Dh=64)
#define BATCH 4
#define SEQ   2048
#define DIM   512
#define NH    8
#define DH    64
#define NTOK  (BATCH*SEQ)        // 8192

typedef __bf16 bf16x8 __attribute__((ext_vector_type(8)));
typedef float  f32x4  __attribute__((ext_vector_type(4)));

#define MFMA16(a,b,c) __builtin_amdgcn_mfma_f32_16x16x32_bf16((a),(b),(c),0,0,0)

// async global->LDS, 16B per lane; LDS dest = wave-uniform base + lane*16
__device__ __forceinline__ void async_ld16(const __bf16* g, __bf16* l) {
  __builtin_amdgcn_global_load_lds(
      (const __attribute__((address_space(1))) void*)g,
      (__attribute__((address_space(3))) void*)l, 16, 0, 0);
}

// ---------------------------------------------------------------------------
// fp32 -> bf16 convert: x (524288 chunks) + 4 weights (131072 chunks), 1 launch
// ---------------------------------------------------------------------------
__global__ __launch_bounds__(256) void cvt_all(
    const float* __restrict__ x,
    const float* __restrict__ s0, const float* __restrict__ s1,
    const float* __restrict__ s2, const float* __restrict__ s3,
    __bf16* __restrict__ xb,
    __bf16* __restrict__ o0, __bf16* __restrict__ o1,
    __bf16* __restrict__ o2, __bf16* __restrict__ o3) {
  int i = blockIdx.x * blockDim.x + threadIdx.x;
  const float* src;
  __bf16* dst;
  int off;
  if (i < NTOK*DIM/8) {
    src = x; dst = xb; off = i;
  } else {
    int w = i - NTOK*DIM/8;
    const int which = w >> 15;
    off = w & 32767;
    src = (which == 0) ? s0 : (which == 1) ? s1 : (which == 2) ? s2 : s3;
    dst = (which == 0) ? o0 : (which == 1) ? o1 : (which == 2) ? o2 : o3;
  }
  const float4* s = (const float4*)src;
  float4 a = s[2*off], b = s[2*off+1];
  bf16x8 o;
  o[0] = (__bf16)a.x; o[1] = (__bf16)a.y; o[2] = (__bf16)a.z; o[3] = (__bf16)a.w;
  o[4] = (__bf16)b.x; o[5] = (__bf16)b.y; o[6] = (__bf16)b.z; o[7] = (__bf16)b.w;
  *(bf16x8*)&dst[8*off] = o;
}

// ---------------------------------------------------------------------------
// NT GEMM 128x128, global_load_lds staging (unpadded LDS stride 64),
// LDS-swizzle epilogue with coalesced 16B stores.
// z = 0/1/2 -> Q / K / V; Q,K stored [B,H,S,Dh]; V stored [B,H,Dh,S]
// ---------------------------------------------------------------------------
__global__ __launch_bounds__(256) void gemm_qkv(
    const __bf16* __restrict__ xb,
    const __bf16* __restrict__ wq, const __bf16* __restrict__ wk,
    const __bf16* __restrict__ wv,
    const float* __restrict__ bq, const float* __restrict__ bk,
    const float* __restrict__ bv,
    __bf16* __restrict__ Qb, __bf16* __restrict__ Kb, __bf16* __restrict__ Vt)
{
  const int z = blockIdx.z;
  const __bf16* W    = (z == 0) ? wq : (z == 1) ? wk : wv;
  const float*  bias = (z == 0) ? bq : (z == 1) ? bk : bv;

  __shared__ __bf16 S[2][128*64];          // As, Bs; reused as C-stage (32 KB)
  __bf16* As = S[0];
  __bf16* Bs = S[1];

  const int tid  = threadIdx.x;
  const int m0   = blockIdx.x * 128, n0 = blockIdx.y * 128;
  const int w    = tid >> 6, lane = tid & 63, quad = lane >> 4, l16 = lane & 15;
  const int wm   = (w >> 1) * 64, wn = (w & 1) * 64;
  const int lrow = lane >> 3;              // 0..7
  const int lcol = (lane & 7) * 8;         // element col within 64

  f32x4 acc[4][4] = {};

  const __bf16* Ag = xb + (size_t)m0 * DIM;
  const __bf16* Bg = W  + (size_t)n0 * DIM;

  for (int k0 = 0; k0 < DIM; k0 += 64) {
#pragma unroll
    for (int i = 0; i < 4; ++i) {
      const int rb = w*32 + i*8;
      async_ld16(&Ag[(size_t)(rb + lrow)*DIM + k0 + lcol], &As[rb*64]);
      async_ld16(&Bg[(size_t)(rb + lrow)*DIM + k0 + lcol], &Bs[rb*64]);
    }
    __syncthreads();
#pragma unroll
    for (int kk = 0; kk < 2; ++kk) {
      const int ko = kk*32 + quad*8;
      bf16x8 af[4], bfr[4];
#pragma unroll
      for (int f = 0; f < 4; ++f) {
        af[f]  = *(const bf16x8*)&As[(wm + f*16 + l16)*64 + ko];
        bfr[f] = *(const bf16x8*)&Bs[(wn + f*16 + l16)*64 + ko];
      }
#pragma unroll
      for (int fm = 0; fm < 4; ++fm)
#pragma unroll
        for (int fn = 0; fn < 4; ++fn)
          acc[fm][fn] = MFMA16(af[fm], bfr[fn], acc[fm][fn]);
    }
    __syncthreads();
  }

  // ---- epilogue: acc -> swizzled LDS tile -> coalesced 16B stores ----
  __bf16* Cs = &S[0][0];                   // 128*128 bf16 = 32 KB (all of S)
  if (z < 2) {
#pragma unroll
    for (int fm = 0; fm < 4; ++fm)
#pragma unroll
      for (int fn = 0; fn < 4; ++fn) {
        const int col = wn + fn*16 + l16;
        const float bc = bias[n0 + col];
        const int chunk = col >> 3, ce = col & 7;
#pragma unroll
        for (int r = 0; r < 4; ++r) {
          const int row = wm + fm*16 + quad*4 + r;
          Cs[row*128 + ((chunk ^ (row & 7)) << 3) + ce] = (__bf16)(acc[fm][fn][r] + bc);
        }
      }
  } else {
#pragma unroll
    for (int fm = 0; fm < 4; ++fm)
#pragma unroll
      for (int fn = 0; fn < 4; ++fn) {
        const int dhcol = wn + fn*16 + l16;
        const float bc = bias[n0 + dhcol];
        const int sbase = wm + fm*16 + quad*4;
        const int schunk = sbase >> 3, so = sbase & 7;
        __bf16* p = &Cs[dhcol*128 + ((schunk ^ (dhcol & 7)) << 3) + so];
#pragma unroll
        for (int r = 0; r < 4; ++r)
          p[r] = (__bf16)(acc[fm][fn][r] + bc);
      }
  }
  __syncthreads();
  {
    const int row = tid >> 1, half = tid & 1;
    if (z < 2) {
      __bf16* O = (z == 0) ? Qb : Kb;
      const int s = m0 + row, bb = s >> 11, ss = s & 2047;
#pragma unroll
      for (int j = 0; j < 8; ++j) {
        const int chunk = half*8 + j;
        bf16x8 v = *(const bf16x8*)&Cs[row*128 + ((chunk ^ (row & 7)) << 3)];
        const int colg = n0 + chunk*8;
        const int hh = colg >> 6, dh = colg & 63;
        *(bf16x8*)&O[((size_t)(bb*NH + hh)*SEQ + ss)*DH + dh] = v;
      }
    } else {
      const int colg = n0 + row;           // dh column
      const int hh = colg >> 6, dh = colg & 63;
      const int bb = m0 >> 11, s0s = m0 & 2047;
#pragma unroll
      for (int j = 0; j < 8; ++j) {
        const int chunk = half*8 + j;
        bf16x8 v = *(const bf16x8*)&Cs[row*128 + ((chunk ^ (row & 7)) << 3)];
        *(bf16x8*)&Vt[((size_t)(bb*NH + hh)*DH + dh)*SEQ + s0s + chunk*8] = v;
      }
    }
  }
}

// ---------------------------------------------------------------------------
// Output projection with the same staging; direct f32 stores.
// ---------------------------------------------------------------------------
__global__ __launch_bounds__(256) void gemm_out(
    const __bf16* __restrict__ attnb, const __bf16* __restrict__ wo,
    const float* __restrict__ bo, float* __restrict__ out)
{
  __shared__ __bf16 S[2][128*64];
  __bf16* As = S[0];
  __bf16* Bs = S[1];

  const int tid = threadIdx.x;
  const int m0  = blockIdx.x * 128, n0 = blockIdx.y * 128;
  const int w   = tid >> 6, lane = tid & 63, quad = lane >> 4, l16 = lane & 15;
  const int wm  = (w >> 1) * 64, wn = (w & 1) * 64;
  const int lrow = lane >> 3, lcol = (lane & 7) * 8;

  f32x4 acc[4][4] = {};

  const __bf16* Ag = attnb + (size_t)m0 * DIM;
  const __bf16* Bg = wo    + (size_t)n0 * DIM;

  for (int k0 = 0; k0 < DIM; k0 += 64) {
#pragma unroll
    for (int i = 0; i < 4; ++i) {
      const int rb = w*32 + i*8;
      async_ld16(&Ag[(size_t)(rb + lrow)*DIM + k0 + lcol], &As[rb*64]);
      async_ld16(&Bg[(size_t)(rb + lrow)*DIM + k0 + lcol], &Bs[rb*64]);
    }
    __syncthreads();
#pragma unroll
    for (int kk = 0; kk < 2; ++kk) {
      const int ko = kk*32 + quad*8;
      bf16x8 af[4], bfr[4];
#pragma unroll
      for (int f = 0; f < 4; ++f) {
        af[f]  = *(const bf16x8*)&As[(wm + f*16 + l16)*64 + ko];
        bfr[f] = *(const bf16x8*)&Bs[(wn + f*16 + l16)*64 + ko];
      }
#pragma unroll
      for (int fm = 0; fm < 4; ++fm)
#pragma unroll
        for (int fn = 0; fn < 4; ++fn)
          acc[fm][fn] = MFMA16(af[fm], bfr[fn], acc[fm][fn]);
    }
    __syncthreads();
  }

#pragma unroll
  for (int fm = 0; fm < 4; ++fm) {
#pragma unroll
    for (int fn = 0; fn < 4; ++fn) {
      const int col  = n0 + wn + fn*16 + l16;
      const float bc = bo[col];
#pragma unroll
      for (int r = 0; r < 4; ++r) {
        const int row = m0 + wm + fm*16 + quad*4 + r;
        out[(size_t)row*DIM + col] = acc[fm][fn][r] + bc;
      }
    }
  }
}

// ---------------------------------------------------------------------------
// Flash v5 part 1: one-wave blocks, global split-K.
// Block = (bh, qt: 32 q-rows, ch: chunk of <=8 64-key tiles). No barriers.
// Writes unnormalized partial O (bf16) + m,l (f32) to workspace.
// ---------------------------------------------------------------------------
__global__ __launch_bounds__(64) void flash_part(
    const __bf16* __restrict__ Qb, const __bf16* __restrict__ Kb,
    const __bf16* __restrict__ Vt,
    __bf16* __restrict__ Op, float* __restrict__ mp, float* __restrict__ lp)
{
  const int idx = blockIdx.x;
  const int bh  = idx & 31;                    // spread across XCDs
  const int ch  = (idx >> 5) & 3;              // chunk fast-varying
  const int qt  = 63 - (idx >> 7);             // heavy q-tiles first
  const int q0  = qt * 32;
  const int nt  = (qt >> 1) + 1;               // 64-key tiles covering [0,q0+32)
  const int nc  = (nt + 7) >> 3;
  if (ch >= nc) return;
  const int ktb = ch * 8;
  const int kte = (ktb + 8 < nt) ? (ktb + 8) : nt;
  const int slot = ((bh << 6) + qt) * 4 + ch;

  const int lane = threadIdx.x & 63, quad = lane >> 4, l16 = lane & 15;

  const __bf16* Qp = Qb + (size_t)bh * SEQ * DH;   // [s][dh]
  const __bf16* Kp = Kb + (size_t)bh * SEQ * DH;   // [s][dh]
  const __bf16* Vp = Vt + (size_t)bh * DH * SEQ;   // [dh][s]

  __shared__ __bf16 Pw[32*72];                 // P transpose patch (one wave)

  // Q fragments, pre-scaled by 1/sqrt(Dh)=0.125 (exact in bf16)
  bf16x8 qf[2][2];
#pragma unroll
  for (int mf = 0; mf < 2; ++mf)
#pragma unroll
    for (int kk = 0; kk < 2; ++kk) {
      bf16x8 q = *(const bf16x8*)&Qp[(size_t)(q0 + mf*16 + l16)*DH + kk*32 + quad*8];
#pragma unroll
      for (int j = 0; j < 8; ++j) q[j] = (__bf16)((float)q[j] * 0.125f);
      qf[mf][kk] = q;
    }

  f32x4 of[2][4] = {};
  float m_[2][4], l_[2][4];
#pragma unroll
  for (int mf = 0; mf < 2; ++mf)
#pragma unroll
    for (int r = 0; r < 4; ++r) { m_[mf][r] = -1e30f; l_[mf][r] = 0.f; }

  bf16x8 kfA[4][2], kfB[4][2];
#pragma unroll
  for (int fn = 0; fn < 4; ++fn)
#pragma unroll
    for (int kk = 0; kk < 2; ++kk)
      kfA[fn][kk] = *(const bf16x8*)&Kp[(size_t)(ktb*64 + fn*16 + l16)*DH + kk*32 + quad*8];

#define TILE_STEP(KC, KN, KT)                                                  \
  {                                                                            \
    const int k0 = (KT) * 64;                                                  \
    bf16x8 vf[4][2];                                                           \
    _Pragma("unroll")                                                          \
    for (int nd = 0; nd < 4; ++nd)                                             \
      _Pragma("unroll")                                                        \
      for (int kq = 0; kq < 2; ++kq)                                           \
        vf[nd][kq] = *(const bf16x8*)&Vp[(size_t)(nd*16 + l16)*SEQ + k0 +      \
                                         kq*32 + quad*8];                      \
    {                                                                          \
      const int kn0 = ((KT) + 1 < kte) ? k0 + 64 : k0;                         \
      _Pragma("unroll")                                                        \
      for (int fn = 0; fn < 4; ++fn)                                           \
        _Pragma("unroll")                                                      \
        for (int kk = 0; kk < 2; ++kk)                                         \
          KN[fn][kk] = *(const bf16x8*)&Kp[(size_t)(kn0 + fn*16 + l16)*DH +    \
                                           kk*32 + quad*8];                    \
    }                                                                          \
    f32x4 sf[2][4] = {};                                                       \
    _Pragma("unroll")                                                          \
    for (int mf = 0; mf < 2; ++mf)                                             \
      _Pragma("unroll")                                                        \
      for (int fn = 0; fn < 4; ++fn) {                                         \
        sf[mf][fn] = MFMA16(qf[mf][0], KC[fn][0], sf[mf][fn]);                 \
        sf[mf][fn] = MFMA16(qf[mf][1], KC[fn][1], sf[mf][fn]);                 \
      }                                                                        \
    if (k0 + 63 > q0) {                                                        \
      _Pragma("unroll")                                                        \
      for (int mf = 0; mf < 2; ++mf)                                           \
        _Pragma("unroll")                                                      \
        for (int fn = 0; fn < 4; ++fn) {                                       \
          const int col = k0 + fn*16 + l16;                                    \
          _Pragma("unroll")                                                    \
          for (int r = 0; r < 4; ++r) {                                        \
            const int row = q0 + mf*16 + quad*4 + r;                           \
            if (col > row) sf[mf][fn][r] = -1e30f;                             \
          }                                                                    \
        }                                                                      \
    }                                                                          \
    float rmax[2][4];                                                          \
    _Pragma("unroll")                                                          \
    for (int mf = 0; mf < 2; ++mf)                                             \
      _Pragma("unroll")                                                        \
      for (int r = 0; r < 4; ++r)                                              \
        rmax[mf][r] = fmaxf(fmaxf(sf[mf][0][r], sf[mf][1][r]),                 \
                            fmaxf(sf[mf][2][r], sf[mf][3][r]));                \
    _Pragma("unroll")                                                          \
    for (int d = 1; d < 16; d <<= 1)                                           \
      _Pragma("unroll")                                                        \
      for (int mf = 0; mf < 2; ++mf)                                           \
        _Pragma("unroll")                                                      \
        for (int r = 0; r < 4; ++r)                                            \
          rmax[mf][r] = fmaxf(rmax[mf][r], __shfl_xor(rmax[mf][r], d));        \
    _Pragma("unroll")                                                          \
    for (int mf = 0; mf < 2; ++mf)                                             \
      _Pragma("unroll")                                                        \
      for (int r = 0; r < 4; ++r) {                                            \
        const float mn = fmaxf(m_[mf][r], rmax[mf][r]);                        \
        const float al = __expf(m_[mf][r] - mn);                               \
        m_[mf][r] = mn;                                                        \
        l_[mf][r] *= al;                                                       \
        _Pragma("unroll")                                                      \
        for (int nd = 0; nd < 4; ++nd) of[mf][nd][r] *= al;                    \
      }                                                                        \
    _Pragma("unroll")                                                          \
    for (int mf = 0; mf < 2; ++mf)                                             \
      _Pragma("unroll")                                                        \
      for (int fn = 0; fn < 4; ++fn)                                           \
        _Pragma("unroll")                                                      \
        for (int r = 0; r < 4; ++r)                                            \
          sf[mf][fn][r] = __expf(sf[mf][fn][r] - m_[mf][r]);                   \
    float rsum[2][4];                                                          \
    _Pragma("unroll")                                                          \
    for (int mf = 0; mf < 2; ++mf)                                             \
      _Pragma("unroll")                                                        \
      for (int r = 0; r < 4; ++r)                                              \
        rsum[mf][r] = (sf[mf][0][r] + sf[mf][1][r]) +                          \
                      (sf[mf][2][r] + sf[mf][3][r]);                           \
    _Pragma("unroll")                                                          \
    for (int d = 1; d < 16; d <<= 1)                                           \
      _Pragma("unroll")                                                        \
      for (int mf = 0; mf < 2; ++mf)                                           \
        _Pragma("unroll")                                                      \
        for (int r = 0; r < 4; ++r)                                            \
          rsum[mf][r] += __shfl_xor(rsum[mf][r], d);                           \
    _Pragma("unroll")                                                          \
    for (int mf = 0; mf < 2; ++mf)                                             \
      _Pragma("unroll")                                                        \
      for (int r = 0; r < 4; ++r) l_[mf][r] += rsum[mf][r];                    \
    _Pragma("unroll")                                                          \
    for (int mf = 0; mf < 2; ++mf)                                             \
      _Pragma("unroll")                                                        \
      for (int fn = 0; fn < 4; ++fn)                                           \
        _Pragma("unroll")                                                      \
        for (int r = 0; r < 4; ++r)                                            \
          Pw[(mf*16 + quad*4 + r)*72 + fn*16 + l16] = (__bf16)sf[mf][fn][r];   \
    bf16x8 pa[2][2];                                                           \
    _Pragma("unroll")                                                          \
    for (int mf = 0; mf < 2; ++mf)                                             \
      _Pragma("unroll")                                                        \
      for (int kq = 0; kq < 2; ++kq)                                           \
        pa[mf][kq] = *(const bf16x8*)&Pw[(mf*16 + l16)*72 + kq*32 + quad*8];   \
    _Pragma("unroll")                                                          \
    for (int mf = 0; mf < 2; ++mf)                                             \
      _Pragma("unroll")                                                        \
      for (int nd = 0; nd < 4; ++nd) {                                         \
        of[mf][nd] = MFMA16(pa[mf][0], vf[nd][0], of[mf][nd]);                 \
        of[mf][nd] = MFMA16(pa[mf][1], vf[nd][1], of[mf][nd]);                 \
      }                                                                        \
  }

  for (int kt = ktb; kt < kte; kt += 2) {
    TILE_STEP(kfA, kfB, kt);
    if (kt + 1 < kte) TILE_STEP(kfB, kfA, kt + 1);
  }
#undef TILE_STEP

  // ---- write partials: O (bf16, unnormalized), m/l (f32) ----
  __bf16* Os = Op + (size_t)slot * 2048;       // [32 rows][64 cols]
#pragma unroll
  for (int mf = 0; mf < 2; ++mf)
#pragma unroll
    for (int nd = 0; nd < 4; ++nd) {
      const int col = nd*16 + l16;
#pragma unroll
      for (int r = 0; r < 4; ++r) {
        const int row = mf*16 + quad*4 + r;
        Os[row*64 + col] = (__bf16)of[mf][nd][r];
      }
    }
  if (l16 == 0) {
#pragma unroll
    for (int mf = 0; mf < 2; ++mf)
#pragma unroll
      for (int r = 0; r < 4; ++r) {
        const int row = mf*16 + quad*4 + r;
        mp[slot*32 + row] = m_[mf][r];
        lp[slot*32 + row] = l_[mf][r];
      }
  }
}

// ---------------------------------------------------------------------------
// Flash v5 part 2: combine <=4 chunk partials per (bh, qt), normalize, store.
// Grid 2048 blocks x 256 thr: thread = (row = tid>>3, 8 cols at (tid&7)*8).
// ---------------------------------------------------------------------------
__global__ __launch_bounds__(256) void flash_reduce(
    const __bf16* __restrict__ Op, const float* __restrict__ mp,
    const float* __restrict__ lp, __bf16* __restrict__ attnb)
{
  const int n  = blockIdx.x;
  const int bh = n & 31, qt = n >> 5;
  const int b  = bh >> 3, h = bh & 7;
  const int q0 = qt * 32;
  const int nt = (qt >> 1) + 1;
  const int nc = (nt + 7) >> 3;
  const int slot0 = ((bh << 6) + qt) * 4;

  const int tid = threadIdx.x;
  const int row = tid >> 3, c8 = (tid & 7) * 8;

  float mi[4], li[4];
  for (int i = 0; i < nc; ++i) {
    mi[i] = mp[(slot0 + i)*32 + row];
    li[i] = lp[(slot0 + i)*32 + row];
  }
  float M = mi[0];
  for (int i = 1; i < nc; ++i) M = fmaxf(M, mi[i]);
  float denom = 0.f, wgt[4];
  for (int i = 0; i < nc; ++i) {
    wgt[i] = __expf(mi[i] - M);
    denom += wgt[i] * li[i];
  }
  const float inv = 1.0f / denom;

  float acc[8] = {};
  for (int i = 0; i < nc; ++i) {
    bf16x8 v = *(const bf16x8*)&Op[(size_t)(slot0 + i)*2048 + row*64 + c8];
    const float wi = wgt[i];
#pragma unroll
    for (int j = 0; j < 8; ++j) acc[j] += wi * (float)v[j];
  }
  bf16x8 o;
#pragma unroll
  for (int j = 0; j < 8; ++j) o[j] = (__bf16)(acc[j] * inv);
  *(bf16x8*)&attnb[((size_t)b*SEQ + q0 + row)*DIM + h*DH + c8] = o;
}

// ---------------------------------------------------------------------------
extern "C" void kernel_launch(void* const* d_in, const int* in_sizes, int n_in,
                              void* d_out, int out_size, void* d_ws, size_t ws_size,
                              hipStream_t stream) {
  const float* x  = (const float*)d_in[0];
  // d_in[1] = causal mask, unused (causality computed analytically)
  const float* Wq = (const float*)d_in[2];
  const float* bq = (const float*)d_in[3];
  const float* Wk = (const float*)d_in[4];
  const float* bk = (const float*)d_in[5];
  const float* Wv = (const float*)d_in[6];
  const float* bv = (const float*)d_in[7];
  const float* Wo = (const float*)d_in[8];
  const float* bo = (const float*)d_in[9];
  float* out = (float*)d_out;

  // workspace carve-up
  __bf16* xb    = (__bf16*)d_ws;
  __bf16* wq    = xb + (size_t)NTOK*DIM;
  __bf16* wk    = wq + DIM*DIM;
  __bf16* wv    = wk + DIM*DIM;
  __bf16* wo    = wv + DIM*DIM;
  __bf16* Qb    = wo + DIM*DIM;
  __bf16* Kb    = Qb + (size_t)NTOK*DIM;
  __bf16* Vt    = Kb + (size_t)NTOK*DIM;
  __bf16* attnb = Vt + (size_t)NTOK*DIM;
  __bf16* Op    = attnb + (size_t)NTOK*DIM;        // 8192 slots x 2048 bf16 (32 MB)
  float*  mp    = (float*)(Op + (size_t)8192*2048);
  float*  lp    = mp + 8192*32;                    // +1 MB each

  cvt_all<<<(NTOK*DIM/8 + 4*DIM*DIM/8)/256, 256, 0, stream>>>(
      x, Wq, Wk, Wv, Wo, xb, wq, wk, wv, wo);

  gemm_qkv<<<dim3(NTOK/128, DIM/128, 3), 256, 0, stream>>>(
      xb, wq, wk, wv, bq, bk, bv, Qb, Kb, Vt);

  flash_part<<<8192, 64, 0, stream>>>(Qb, Kb, Vt, Op, mp, lp);
  flash_reduce<<<2048, 256, 0, stream>>>(Op, mp, lp, attnb);

  gemm_out<<<dim3(NTOK/128, DIM/128), 256, 0, stream>>>(attnb, wo, bo, out);
}

// Round 6
// 215.603 us; speedup vs baseline: 1.1535x; 1.0951x over previous
//
#include <hip/hip_runtime.h>
#include <hip/hip_bf16.h>

// Problem constants (B=4, S=2048, D=512, H=8, Dh=64)
#define BATCH 4
#define SEQ   2048
#define DIM   512
#define NH    8
#define DH    64
#define NTOK  (BATCH*SEQ)        // 8192

typedef __bf16 bf16x8 __attribute__((ext_vector_type(8)));
typedef __bf16 bf16x4 __attribute__((ext_vector_type(4)));
typedef float  f32x4  __attribute__((ext_vector_type(4)));

#define MFMA16(a,b,c) __builtin_amdgcn_mfma_f32_16x16x32_bf16((a),(b),(c),0,0,0)

// async global->LDS, 16B per lane; LDS dest = wave-uniform base + lane*16
__device__ __forceinline__ void async_ld16(const __bf16* g, __bf16* l) {
  __builtin_amdgcn_global_load_lds(
      (const __attribute__((address_space(1))) void*)g,
      (__attribute__((address_space(3))) void*)l, 16, 0, 0);
}

// ---------------------------------------------------------------------------
// fp32 -> bf16 convert: x (524288 chunks) + 4 weights (131072 chunks), 1 launch
// ---------------------------------------------------------------------------
__global__ __launch_bounds__(256) void cvt_all(
    const float* __restrict__ x,
    const float* __restrict__ s0, const float* __restrict__ s1,
    const float* __restrict__ s2, const float* __restrict__ s3,
    __bf16* __restrict__ xb,
    __bf16* __restrict__ o0, __bf16* __restrict__ o1,
    __bf16* __restrict__ o2, __bf16* __restrict__ o3) {
  int i = blockIdx.x * blockDim.x + threadIdx.x;
  const float* src;
  __bf16* dst;
  int off;
  if (i < NTOK*DIM/8) {
    src = x; dst = xb; off = i;
  } else {
    int w = i - NTOK*DIM/8;
    const int which = w >> 15;
    off = w & 32767;
    src = (which == 0) ? s0 : (which == 1) ? s1 : (which == 2) ? s2 : s3;
    dst = (which == 0) ? o0 : (which == 1) ? o1 : (which == 2) ? o2 : o3;
  }
  const float4* s = (const float4*)src;
  float4 a = s[2*off], b = s[2*off+1];
  bf16x8 o;
  o[0] = (__bf16)a.x; o[1] = (__bf16)a.y; o[2] = (__bf16)a.z; o[3] = (__bf16)a.w;
  o[4] = (__bf16)b.x; o[5] = (__bf16)b.y; o[6] = (__bf16)b.z; o[7] = (__bf16)b.w;
  *(bf16x8*)&dst[8*off] = o;
}

// ---------------------------------------------------------------------------
// NT GEMM 128x128, global_load_lds staging (unpadded LDS stride 64),
// LDS-swizzle epilogue with coalesced 16B stores.
// z = 0/1/2 -> Q / K / V; Q,K stored [B,H,S,Dh]; V stored [B,H,Dh,S]
// ---------------------------------------------------------------------------
__global__ __launch_bounds__(256) void gemm_qkv(
    const __bf16* __restrict__ xb,
    const __bf16* __restrict__ wq, const __bf16* __restrict__ wk,
    const __bf16* __restrict__ wv,
    const float* __restrict__ bq, const float* __restrict__ bk,
    const float* __restrict__ bv,
    __bf16* __restrict__ Qb, __bf16* __restrict__ Kb, __bf16* __restrict__ Vt)
{
  const int z = blockIdx.z;
  const __bf16* W    = (z == 0) ? wq : (z == 1) ? wk : wv;
  const float*  bias = (z == 0) ? bq : (z == 1) ? bk : bv;

  __shared__ __bf16 S[2][128*64];          // As, Bs; reused as C-stage (32 KB)
  __bf16* As = S[0];
  __bf16* Bs = S[1];

  const int tid  = threadIdx.x;
  const int m0   = blockIdx.x * 128, n0 = blockIdx.y * 128;
  const int w    = tid >> 6, lane = tid & 63, quad = lane >> 4, l16 = lane & 15;
  const int wm   = (w >> 1) * 64, wn = (w & 1) * 64;
  const int lrow = lane >> 3;              // 0..7
  const int lcol = (lane & 7) * 8;         // element col within 64

  f32x4 acc[4][4] = {};

  const __bf16* Ag = xb + (size_t)m0 * DIM;
  const __bf16* Bg = W  + (size_t)n0 * DIM;

  for (int k0 = 0; k0 < DIM; k0 += 64) {
#pragma unroll
    for (int i = 0; i < 4; ++i) {
      const int rb = w*32 + i*8;
      async_ld16(&Ag[(size_t)(rb + lrow)*DIM + k0 + lcol], &As[rb*64]);
      async_ld16(&Bg[(size_t)(rb + lrow)*DIM + k0 + lcol], &Bs[rb*64]);
    }
    __syncthreads();
#pragma unroll
    for (int kk = 0; kk < 2; ++kk) {
      const int ko = kk*32 + quad*8;
      bf16x8 af[4], bfr[4];
#pragma unroll
      for (int f = 0; f < 4; ++f) {
        af[f]  = *(const bf16x8*)&As[(wm + f*16 + l16)*64 + ko];
        bfr[f] = *(const bf16x8*)&Bs[(wn + f*16 + l16)*64 + ko];
      }
#pragma unroll
      for (int fm = 0; fm < 4; ++fm)
#pragma unroll
        for (int fn = 0; fn < 4; ++fn)
          acc[fm][fn] = MFMA16(af[fm], bfr[fn], acc[fm][fn]);
    }
    __syncthreads();
  }

  // ---- epilogue: acc -> swizzled LDS tile -> coalesced 16B stores ----
  __bf16* Cs = &S[0][0];                   // 128*128 bf16 = 32 KB (all of S)
  if (z < 2) {
#pragma unroll
    for (int fm = 0; fm < 4; ++fm)
#pragma unroll
      for (int fn = 0; fn < 4; ++fn) {
        const int col = wn + fn*16 + l16;
        const float bc = bias[n0 + col];
        const int chunk = col >> 3, ce = col & 7;
#pragma unroll
        for (int r = 0; r < 4; ++r) {
          const int row = wm + fm*16 + quad*4 + r;
          Cs[row*128 + ((chunk ^ (row & 7)) << 3) + ce] = (__bf16)(acc[fm][fn][r] + bc);
        }
      }
  } else {
#pragma unroll
    for (int fm = 0; fm < 4; ++fm)
#pragma unroll
      for (int fn = 0; fn < 4; ++fn) {
        const int dhcol = wn + fn*16 + l16;
        const float bc = bias[n0 + dhcol];
        const int sbase = wm + fm*16 + quad*4;
        const int schunk = sbase >> 3, so = sbase & 7;
        __bf16* p = &Cs[dhcol*128 + ((schunk ^ (dhcol & 7)) << 3) + so];
#pragma unroll
        for (int r = 0; r < 4; ++r)
          p[r] = (__bf16)(acc[fm][fn][r] + bc);
      }
  }
  __syncthreads();
  {
    const int row = tid >> 1, half = tid & 1;
    if (z < 2) {
      __bf16* O = (z == 0) ? Qb : Kb;
      const int s = m0 + row, bb = s >> 11, ss = s & 2047;
#pragma unroll
      for (int j = 0; j < 8; ++j) {
        const int chunk = half*8 + j;
        bf16x8 v = *(const bf16x8*)&Cs[row*128 + ((chunk ^ (row & 7)) << 3)];
        const int colg = n0 + chunk*8;
        const int hh = colg >> 6, dh = colg & 63;
        *(bf16x8*)&O[((size_t)(bb*NH + hh)*SEQ + ss)*DH + dh] = v;
      }
    } else {
      const int colg = n0 + row;           // dh column
      const int hh = colg >> 6, dh = colg & 63;
      const int bb = m0 >> 11, s0s = m0 & 2047;
#pragma unroll
      for (int j = 0; j < 8; ++j) {
        const int chunk = half*8 + j;
        bf16x8 v = *(const bf16x8*)&Cs[row*128 + ((chunk ^ (row & 7)) << 3)];
        *(bf16x8*)&Vt[((size_t)(bb*NH + hh)*DH + dh)*SEQ + s0s + chunk*8] = v;
      }
    }
  }
}

// ---------------------------------------------------------------------------
// Output projection with the same staging; direct f32 stores.
// ---------------------------------------------------------------------------
__global__ __launch_bounds__(256) void gemm_out(
    const __bf16* __restrict__ attnb, const __bf16* __restrict__ wo,
    const float* __restrict__ bo, float* __restrict__ out)
{
  __shared__ __bf16 S[2][128*64];
  __bf16* As = S[0];
  __bf16* Bs = S[1];

  const int tid = threadIdx.x;
  const int m0  = blockIdx.x * 128, n0 = blockIdx.y * 128;
  const int w   = tid >> 6, lane = tid & 63, quad = lane >> 4, l16 = lane & 15;
  const int wm  = (w >> 1) * 64, wn = (w & 1) * 64;
  const int lrow = lane >> 3, lcol = (lane & 7) * 8;

  f32x4 acc[4][4] = {};

  const __bf16* Ag = attnb + (size_t)m0 * DIM;
  const __bf16* Bg = wo    + (size_t)n0 * DIM;

  for (int k0 = 0; k0 < DIM; k0 += 64) {
#pragma unroll
    for (int i = 0; i < 4; ++i) {
      const int rb = w*32 + i*8;
      async_ld16(&Ag[(size_t)(rb + lrow)*DIM + k0 + lcol], &As[rb*64]);
      async_ld16(&Bg[(size_t)(rb + lrow)*DIM + k0 + lcol], &Bs[rb*64]);
    }
    __syncthreads();
#pragma unroll
    for (int kk = 0; kk < 2; ++kk) {
      const int ko = kk*32 + quad*8;
      bf16x8 af[4], bfr[4];
#pragma unroll
      for (int f = 0; f < 4; ++f) {
        af[f]  = *(const bf16x8*)&As[(wm + f*16 + l16)*64 + ko];
        bfr[f] = *(const bf16x8*)&Bs[(wn + f*16 + l16)*64 + ko];
      }
#pragma unroll
      for (int fm = 0; fm < 4; ++fm)
#pragma unroll
        for (int fn = 0; fn < 4; ++fn)
          acc[fm][fn] = MFMA16(af[fm], bfr[fn], acc[fm][fn]);
    }
    __syncthreads();
  }

#pragma unroll
  for (int fm = 0; fm < 4; ++fm) {
#pragma unroll
    for (int fn = 0; fn < 4; ++fn) {
      const int col  = n0 + wn + fn*16 + l16;
      const float bc = bo[col];
#pragma unroll
      for (int r = 0; r < 4; ++r) {
        const int row = m0 + wm + fm*16 + quad*4 + r;
        out[(size_t)row*DIM + col] = acc[fm][fn][r] + bc;
      }
    }
  }
}

// ---------------------------------------------------------------------------
// Flash v6: S^T orientation. One wave per (bh, 32 q-rows), heavy-first.
//   S^T = K x Q^T  (A = K-frag, B = Q-frag)  -> q lives in lane index l16,
//   so m/l/alpha are per-lane SCALARS; key-reduction = 15 in-reg ops + 2 shfl.
//   P^T: 4 C-regs = 4 consecutive keys -> 8 x ds_write_b64, 4 x ds_read_b128.
//   O^T = V^T x P^T (A = V-frag straight from Vt[dh][s]).
// K(t+1)/V(t+1) issued early (single buffer), consumed a softmax later.
// ---------------------------------------------------------------------------
__global__ __launch_bounds__(64) void flash_attn(
    const __bf16* __restrict__ Qb, const __bf16* __restrict__ Kb,
    const __bf16* __restrict__ Vt, __bf16* __restrict__ attnb)
{
  const int idx = blockIdx.x;
  const int bh  = idx & 31;                    // spread across XCDs
  const int qt  = 63 - (idx >> 5);             // heavy q-tiles dispatch first
  const int b   = bh >> 3, h = bh & 7;
  const int lane = threadIdx.x & 63, quad = lane >> 4, l16 = lane & 15;
  const int q0  = qt * 32;

  const __bf16* Qp = Qb + (size_t)bh * SEQ * DH;   // [s][dh]
  const __bf16* Kp = Kb + (size_t)bh * SEQ * DH;   // [s][dh]
  const __bf16* Vp = Vt + (size_t)bh * DH * SEQ;   // [dh][s]

  __shared__ __bf16 Pt[32*72];                 // P^T patch [q][key], stride 72

  // Q B-frags, pre-scaled by 1/sqrt(Dh)=0.125 (exact in bf16)
  bf16x8 qf[2][2];                             // [nf][kc]
#pragma unroll
  for (int nf = 0; nf < 2; ++nf)
#pragma unroll
    for (int kc = 0; kc < 2; ++kc) {
      bf16x8 q = *(const bf16x8*)&Qp[(size_t)(q0 + nf*16 + l16)*DH + kc*32 + quad*8];
#pragma unroll
      for (int j = 0; j < 8; ++j) q[j] = (__bf16)((float)q[j] * 0.125f);
      qf[nf][kc] = q;
    }

  f32x4 o[4][2] = {};                          // O^T accum [dhf][nf]
  float m_[2] = {-1e30f, -1e30f}, l_[2] = {0.f, 0.f};

  const int nt = (q0 >> 6) + 1;                // 64-key tiles covering [0,q0+32)

  bf16x8 kf[4][2];                             // K-frags [mf(key)][kc(d)]
  bf16x8 vf[4][2];                             // V-frags [dhf][kc(key)]
#pragma unroll
  for (int mf = 0; mf < 4; ++mf)
#pragma unroll
    for (int kc = 0; kc < 2; ++kc)
      kf[mf][kc] = *(const bf16x8*)&Kp[(size_t)(mf*16 + l16)*DH + kc*32 + quad*8];
#pragma unroll
  for (int df = 0; df < 4; ++df)
#pragma unroll
    for (int kc = 0; kc < 2; ++kc)
      vf[df][kc] = *(const bf16x8*)&Vp[(size_t)(df*16 + l16)*SEQ + kc*32 + quad*8];

  for (int kt = 0; kt < nt; ++kt) {
    const int k0 = kt * 64;
    const int kn0 = (kt + 1 < nt) ? k0 + 64 : k0;

    // ---- S^T = K Q^T : 16 MFMAs, C[key][q] ----
    f32x4 s[4][2] = {};
#pragma unroll
    for (int mf = 0; mf < 4; ++mf)
#pragma unroll
      for (int nf = 0; nf < 2; ++nf) {
        s[mf][nf] = MFMA16(kf[mf][0], qf[nf][0], s[mf][nf]);
        s[mf][nf] = MFMA16(kf[mf][1], qf[nf][1], s[mf][nf]);
      }

    // ---- early-issue K(t+1) (consumed next QK, a full softmax away) ----
#pragma unroll
    for (int mf = 0; mf < 4; ++mf)
#pragma unroll
      for (int kc = 0; kc < 2; ++kc)
        kf[mf][kc] = *(const bf16x8*)&Kp[(size_t)(kn0 + mf*16 + l16)*DH + kc*32 + quad*8];

    // ---- causal mask (last tile(s) only). key=k0+mf*16+quad*4+r, q=lane ----
    if (k0 + 63 > q0) {
#pragma unroll
      for (int nf = 0; nf < 2; ++nf) {
        const int q = q0 + nf*16 + l16;
#pragma unroll
        for (int mf = 0; mf < 4; ++mf) {
          const int kb = k0 + mf*16 + quad*4;
#pragma unroll
          for (int r = 0; r < 4; ++r)
            if (kb + r > q) s[mf][nf][r] = -1e30f;
        }
      }
    }

    // ---- per-lane softmax (q = lane) ----
#pragma unroll
    for (int nf = 0; nf < 2; ++nf) {
      float mx = fmaxf(fmaxf(fmaxf(s[0][nf][0], s[0][nf][1]), fmaxf(s[0][nf][2], s[0][nf][3])),
                       fmaxf(fmaxf(s[1][nf][0], s[1][nf][1]), fmaxf(s[1][nf][2], s[1][nf][3])));
      float mx2 = fmaxf(fmaxf(fmaxf(s[2][nf][0], s[2][nf][1]), fmaxf(s[2][nf][2], s[2][nf][3])),
                        fmaxf(fmaxf(s[3][nf][0], s[3][nf][1]), fmaxf(s[3][nf][2], s[3][nf][3])));
      mx = fmaxf(mx, mx2);
      mx = fmaxf(mx, __shfl_xor(mx, 16));
      mx = fmaxf(mx, __shfl_xor(mx, 32));
      const float mn = fmaxf(m_[nf], mx);
      const float al = __expf(m_[nf] - mn);
      m_[nf] = mn;
      float sum = 0.f;
#pragma unroll
      for (int mf = 0; mf < 4; ++mf)
#pragma unroll
        for (int r = 0; r < 4; ++r) {
          const float e = __expf(s[mf][nf][r] - mn);
          s[mf][nf][r] = e;
          sum += e;
        }
      sum += __shfl_xor(sum, 16);
      sum += __shfl_xor(sum, 32);
      l_[nf] = l_[nf] * al + sum;
#pragma unroll
      for (int df = 0; df < 4; ++df)
#pragma unroll
        for (int r = 0; r < 4; ++r)
          o[df][nf][r] *= al;
    }

    // ---- P^T -> LDS (vectorized b64 writes), read back as B-frags ----
#pragma unroll
    for (int nf = 0; nf < 2; ++nf)
#pragma unroll
      for (int mf = 0; mf < 4; ++mf) {
        bf16x4 p4;
#pragma unroll
        for (int r = 0; r < 4; ++r) p4[r] = (__bf16)s[mf][nf][r];
        *(bf16x4*)&Pt[(nf*16 + l16)*72 + mf*16 + quad*4] = p4;
      }
    bf16x8 pb[2][2];                           // [nf][kc(key)]
#pragma unroll
    for (int nf = 0; nf < 2; ++nf)
#pragma unroll
      for (int kc = 0; kc < 2; ++kc)
        pb[nf][kc] = *(const bf16x8*)&Pt[(nf*16 + l16)*72 + kc*32 + quad*8];

    // ---- O^T += V^T P^T : 16 MFMAs ----
#pragma unroll
    for (int df = 0; df < 4; ++df)
#pragma unroll
      for (int nf = 0; nf < 2; ++nf) {
        o[df][nf] = MFMA16(vf[df][0], pb[nf][0], o[df][nf]);
        o[df][nf] = MFMA16(vf[df][1], pb[nf][1], o[df][nf]);
      }

    // ---- early-issue V(t+1) (consumed next PV) ----
#pragma unroll
    for (int df = 0; df < 4; ++df)
#pragma unroll
      for (int kc = 0; kc < 2; ++kc)
        vf[df][kc] = *(const bf16x8*)&Vp[(size_t)(df*16 + l16)*SEQ + kn0 + kc*32 + quad*8];
  }

  // ---- normalize + store: O^T col=q=l16, row=dh=df*16+quad*4+r ----
#pragma unroll
  for (int nf = 0; nf < 2; ++nf) {
    const float inv = 1.0f / l_[nf];
    const int q = q0 + nf*16 + l16;
#pragma unroll
    for (int df = 0; df < 4; ++df) {
      bf16x4 o4;
#pragma unroll
      for (int r = 0; r < 4; ++r) o4[r] = (__bf16)(o[df][nf][r] * inv);
      *(bf16x4*)&attnb[((size_t)b*SEQ + q)*DIM + h*DH + df*16 + quad*4] = o4;
    }
  }
}

// ---------------------------------------------------------------------------
extern "C" void kernel_launch(void* const* d_in, const int* in_sizes, int n_in,
                              void* d_out, int out_size, void* d_ws, size_t ws_size,
                              hipStream_t stream) {
  const float* x  = (const float*)d_in[0];
  // d_in[1] = causal mask, unused (causality computed analytically)
  const float* Wq = (const float*)d_in[2];
  const float* bq = (const float*)d_in[3];
  const float* Wk = (const float*)d_in[4];
  const float* bk = (const float*)d_in[5];
  const float* Wv = (const float*)d_in[6];
  const float* bv = (const float*)d_in[7];
  const float* Wo = (const float*)d_in[8];
  const float* bo = (const float*)d_in[9];
  float* out = (float*)d_out;

  // workspace carve-up (bf16 elements)
  __bf16* xb    = (__bf16*)d_ws;
  __bf16* wq    = xb + (size_t)NTOK*DIM;
  __bf16* wk    = wq + DIM*DIM;
  __bf16* wv    = wk + DIM*DIM;
  __bf16* wo    = wv + DIM*DIM;
  __bf16* Qb    = wo + DIM*DIM;
  __bf16* Kb    = Qb + (size_t)NTOK*DIM;
  __bf16* Vt    = Kb + (size_t)NTOK*DIM;
  __bf16* attnb = Vt + (size_t)NTOK*DIM;

  cvt_all<<<(NTOK*DIM/8 + 4*DIM*DIM/8)/256, 256, 0, stream>>>(
      x, Wq, Wk, Wv, Wo, xb, wq, wk, wv, wo);

  gemm_qkv<<<dim3(NTOK/128, DIM/128, 3), 256, 0, stream>>>(
      xb, wq, wk, wv, bq, bk, bv, Qb, Kb, Vt);

  flash_attn<<<2048, 64, 0, stream>>>(Qb, Kb, Vt, attnb);

  gemm_out<<<dim3(NTOK/128, DIM/128), 256, 0, stream>>>(attnb, wo, bo, out);
}